// Round 9
// baseline (319.336 us; speedup 1.0000x reference)
//
#include <hip/hip_runtime.h>
#include <hip/hip_bf16.h>
#include <math.h>

#define B_SZ   4096
#define H_LEN  256
#define D_DIM  128
#define K_HEADS 4
#define H1_DIM 512
#define H2_DIM 256
#define NUM_ITEMS 200000

#define CH     64     // fp32 path: rows per chunk
#define NCH    4
#define TPAD   132    // fp32 tile row stride (floats)
#define H1PAD  520    // fused_mlp H1 LDS stride (bf16)

#define CH2    128    // fp16 path: rows per chunk
#define NCH2   2
#define TP2    136    // fp16 tile row stride (halves): 272 B = 17*16, b128-aligned

typedef __attribute__((ext_vector_type(8))) short bf16x8;   // 8 bf16 (4 VGPRs)
typedef __attribute__((ext_vector_type(4))) float f32x4;
typedef _Float16 fp16x8 __attribute__((ext_vector_type(8)));

// ---------------------------------------------------------------------------
// Table fp32 -> fp16 streaming convert (runs every call; table is restored by
// the harness before each timed launch). 3.2M threads x 8 elems.
// ---------------------------------------------------------------------------
__global__ __launch_bounds__(256) void convert_table(
    const float* __restrict__ table, _Float16* __restrict__ t16)
{
    const int tid = blockIdx.x * 256 + threadIdx.x;   // [0, 3.2M)
    float4 a = ((const float4*)table)[tid * 2];
    float4 b = ((const float4*)table)[tid * 2 + 1];
    fp16x8 h;
    h[0] = (_Float16)a.x; h[1] = (_Float16)a.y;
    h[2] = (_Float16)a.z; h[3] = (_Float16)a.w;
    h[4] = (_Float16)b.x; h[5] = (_Float16)b.y;
    h[6] = (_Float16)b.z; h[7] = (_Float16)b.w;
    ((fp16x8*)t16)[tid] = h;
}

// ---------------------------------------------------------------------------
// Shared epilogue macro-free helper: weight-conversion side blocks
// ---------------------------------------------------------------------------
__device__ __forceinline__ void weight_convert_block(
    int blk, int t, const float* W1, const float* W2,
    __hip_bfloat16* W1t, __hip_bfloat16* W2t)
{
    int idx = blk * 256 + t;
    if (idx < 2 * D_DIM * H1_DIM) {              // W1t[n][k] = W1[k][n]
        int n = idx >> 8, k = idx & 255;
        W1t[idx] = __float2bfloat16(W1[k * H1_DIM + n]);
    } else {                                     // W2t[n][k] = W2[k][n]
        int j = idx - 2 * D_DIM * H1_DIM;
        int n = j >> 9, k = j & 511;
        W2t[j] = __float2bfloat16(W2[k * H2_DIM + n]);
    }
}

// ---------------------------------------------------------------------------
// Kernel 1a (fp16 path): multi-interest extraction gathering fp16 rows.
// 2 lanes/row x 8 b128 loads (same in-flight depth as the 107us fp32 body),
// CH2=128 rows/chunk, 2 chunks. Scores & pooling accumulate fp32; candidate
// row read from the fp32 table (exact). LDS 40.6 KB -> 4 blocks/CU.
// ---------------------------------------------------------------------------
__global__ __launch_bounds__(256, 2) void interest_kernel_f16(
    const int*   __restrict__ cand_ids,
    const int*   __restrict__ hist,
    const float* __restrict__ table,      // fp32 (for candidate row)
    const _Float16* __restrict__ t16,     // fp16 table cache
    const float* __restrict__ Wp,
    const float* __restrict__ W1, const float* __restrict__ W2,
    __hip_bfloat16* __restrict__ W1t, __hip_bfloat16* __restrict__ W2t,
    __hip_bfloat16* __restrict__ Xbf)
{
    if (blockIdx.x >= B_SZ) {
        weight_convert_block(blockIdx.x - B_SZ, threadIdx.x, W1, W2, W1t, W2t);
        return;
    }

    __shared__ __align__(16) _Float16 tile_h[CH2 * TP2];  // 34816 B
    __shared__ float wpt[K_HEADS * D_DIM];                // 2 KB
    __shared__ float exps4[CH2 * 4];                      // 2 KB
    __shared__ float candv[D_DIM];                        // 512 B
    __shared__ int   rowids[H_LEN];                       // 1 KB
    __shared__ float lsumW[16];
    __shared__ float simred[4][K_HEADS];
    __shared__ int   bestk;

    const int b    = blockIdx.x;
    const int t    = threadIdx.x;
    const int lane = t & 63, w = t >> 6;
    const int rr   = t >> 1, q = t & 1;      // 128 rows/chunk, 2 lanes/row
    const int d    = t & 127, half = t >> 7;

    if (t < D_DIM) {
        float4 w4 = ((const float4*)Wp)[t];
        wpt[0 * D_DIM + t] = w4.x;
        wpt[1 * D_DIM + t] = w4.y;
        wpt[2 * D_DIM + t] = w4.z;
        wpt[3 * D_DIM + t] = w4.w;
    }
    const int cand = cand_ids[b];
    if (t >= 128 && t < 160) {
        int c = t - 128;
        ((float4*)candv)[c] = ((const float4*)(table + (long long)cand * D_DIM))[c];
    }
    rowids[t] = hist[(long long)b * H_LEN + t];

    float a0 = 0.f, a1 = 0.f, a2 = 0.f, a3 = 0.f;
    float l0 = 0.f, l1 = 0.f, l2 = 0.f, l3 = 0.f;

    for (int c = 0; c < NCH2; ++c) {
        __syncthreads();

        const int row = rowids[(c << 7) + rr];
        const fp16x8* rp = (const fp16x8*)(t16 + (long long)row * D_DIM + (q << 6));
        fp16x8 v0 = rp[0], v1 = rp[1], v2 = rp[2], v3 = rp[3];
        fp16x8 v4 = rp[4], v5 = rp[5], v6 = rp[6], v7 = rp[7];

        float s0 = 0.f, s1 = 0.f, s2 = 0.f, s3 = 0.f;
        #define DO_J(J, VV)                                                     \
        {   fp16x8 va = VV;                                                     \
            const int db = (q << 6) + (J << 3);                                 \
            float ax = (float)va[0], ay = (float)va[1];                         \
            float az = (float)va[2], aw = (float)va[3];                         \
            float bx = (float)va[4], by = (float)va[5];                         \
            float bz = (float)va[6], bw = (float)va[7];                         \
            float4 w0l = *(const float4*)(wpt + 0 * D_DIM + db);                \
            float4 w0h = *(const float4*)(wpt + 0 * D_DIM + db + 4);            \
            float4 w1l = *(const float4*)(wpt + 1 * D_DIM + db);                \
            float4 w1h = *(const float4*)(wpt + 1 * D_DIM + db + 4);            \
            float4 w2l = *(const float4*)(wpt + 2 * D_DIM + db);                \
            float4 w2h = *(const float4*)(wpt + 2 * D_DIM + db + 4);            \
            float4 w3l = *(const float4*)(wpt + 3 * D_DIM + db);                \
            float4 w3h = *(const float4*)(wpt + 3 * D_DIM + db + 4);            \
            s0 += ax*w0l.x + ay*w0l.y + az*w0l.z + aw*w0l.w                     \
                + bx*w0h.x + by*w0h.y + bz*w0h.z + bw*w0h.w;                    \
            s1 += ax*w1l.x + ay*w1l.y + az*w1l.z + aw*w1l.w                     \
                + bx*w1h.x + by*w1h.y + bz*w1h.z + bw*w1h.w;                    \
            s2 += ax*w2l.x + ay*w2l.y + az*w2l.z + aw*w2l.w                     \
                + bx*w2h.x + by*w2h.y + bz*w2h.z + bw*w2h.w;                    \
            s3 += ax*w3l.x + ay*w3l.y + az*w3l.z + aw*w3l.w                     \
                + bx*w3h.x + by*w3h.y + bz*w3h.z + bw*w3h.w;                    \
            *(fp16x8*)(tile_h + rr * TP2 + db) = va;                            \
        }
        DO_J(0, v0) DO_J(1, v1) DO_J(2, v2) DO_J(3, v3)
        DO_J(4, v4) DO_J(5, v5) DO_J(6, v6) DO_J(7, v7)
        #undef DO_J

        // combine the 2 q-lanes of each row
        s0 += __shfl_xor(s0, 1);
        s1 += __shfl_xor(s1, 1);
        s2 += __shfl_xor(s2, 1);
        s3 += __shfl_xor(s3, 1);

        float e0 = expf(s0), e1 = expf(s1), e2 = expf(s2), e3 = expf(s3);
        if (q == 0) ((float4*)exps4)[rr] = make_float4(e0, e1, e2, e3);

        // wave-sum over this wave's 32 rows (parity classes hold each row once)
        float t0 = e0, t1 = e1, t2 = e2, t3 = e3;
        #pragma unroll
        for (int off = 2; off <= 32; off <<= 1) {
            t0 += __shfl_xor(t0, off);
            t1 += __shfl_xor(t1, off);
            t2 += __shfl_xor(t2, off);
            t3 += __shfl_xor(t3, off);
        }
        l0 += t0; l1 += t1; l2 += t2; l3 += t3;

        __syncthreads();

        // pooling: (d, half) accumulates 64 chunk rows
        #pragma unroll 8
        for (int i = 0; i < 64; ++i) {
            int hl = (half << 6) + i;
            float4 e4 = ((const float4*)exps4)[hl];        // broadcast
            float  vv = (float)tile_h[hl * TP2 + d];       // same-word pairs
            a0 += e4.x * vv; a1 += e4.y * vv; a2 += e4.z * vv; a3 += e4.w * vv;
        }
    }

    __syncthreads();
    float* partBp = (float*)tile_h;
    float* ivbufp = (float*)tile_h + 512;

    if (half == 1) ((float4*)partBp)[d] = make_float4(a0, a1, a2, a3);
    if (lane == 0) ((float4*)lsumW)[w]  = make_float4(l0, l1, l2, l3);
    __syncthreads();

    float s0 = 0.f, s1 = 0.f, s2 = 0.f, s3 = 0.f;
    if (half == 0) {
        float4 pb = ((const float4*)partBp)[d];
        float4 L0 = ((const float4*)lsumW)[0];
        float4 L1 = ((const float4*)lsumW)[1];
        float4 L2 = ((const float4*)lsumW)[2];
        float4 L3 = ((const float4*)lsumW)[3];
        float i0 = 1.f / (L0.x + L1.x + L2.x + L3.x);
        float i1 = 1.f / (L0.y + L1.y + L2.y + L3.y);
        float i2 = 1.f / (L0.z + L1.z + L2.z + L3.z);
        float i3 = 1.f / (L0.w + L1.w + L2.w + L3.w);
        a0 = (a0 + pb.x) * i0;
        a1 = (a1 + pb.y) * i1;
        a2 = (a2 + pb.z) * i2;
        a3 = (a3 + pb.w) * i3;
        ((float4*)ivbufp)[d] = make_float4(a0, a1, a2, a3);
        float cd = candv[d];
        s0 = a0 * cd; s1 = a1 * cd; s2 = a2 * cd; s3 = a3 * cd;
    }
    #pragma unroll
    for (int off = 32; off >= 1; off >>= 1) {
        s0 += __shfl_xor(s0, off);
        s1 += __shfl_xor(s1, off);
        s2 += __shfl_xor(s2, off);
        s3 += __shfl_xor(s3, off);
    }
    if (lane == 0) {
        simred[w][0] = s0; simred[w][1] = s1;
        simred[w][2] = s2; simred[w][3] = s3;
    }
    __syncthreads();

    if (t == 0) {
        float sim[4];
        #pragma unroll
        for (int k = 0; k < 4; ++k)
            sim[k] = simred[0][k] + simred[1][k] + simred[2][k] + simred[3][k];
        int best = 0;
        #pragma unroll
        for (int k = 1; k < 4; ++k) if (sim[k] > sim[best]) best = k;  // first-max
        bestk = best;
    }
    __syncthreads();

    __hip_bfloat16* xrow = Xbf + (long long)b * (2 * D_DIM);
    if (t < 128) xrow[t] = __float2bfloat16(ivbufp[t * 4 + bestk]);
    else         xrow[t] = __float2bfloat16(candv[t - 128]);
}

// ---------------------------------------------------------------------------
// Kernel 1b (fallback, round-8 body verbatim): fp32 gather path.
// ---------------------------------------------------------------------------
__global__ __launch_bounds__(256, 4) void interest_kernel_f32(
    const int*   __restrict__ cand_ids,
    const int*   __restrict__ hist,
    const float* __restrict__ table,
    const float* __restrict__ Wp,
    const float* __restrict__ W1, const float* __restrict__ W2,
    __hip_bfloat16* __restrict__ W1t, __hip_bfloat16* __restrict__ W2t,
    __hip_bfloat16* __restrict__ Xbf)
{
    if (blockIdx.x >= B_SZ) {
        weight_convert_block(blockIdx.x - B_SZ, threadIdx.x, W1, W2, W1t, W2t);
        return;
    }

    __shared__ float tile[CH * TPAD];
    __shared__ float wpt[K_HEADS * D_DIM];
    __shared__ float exps4[CH * 4];
    __shared__ float candv[D_DIM];
    __shared__ int   rowids[H_LEN];
    __shared__ float lsumW[16];
    __shared__ float simred[4][K_HEADS];
    __shared__ int   bestk;

    const int b    = blockIdx.x;
    const int t    = threadIdx.x;
    const int lane = t & 63, w = t >> 6;
    const int r    = t >> 2, q = t & 3;
    const int d    = t & 127, half = t >> 7;

    if (t < D_DIM) {
        float4 w4 = ((const float4*)Wp)[t];
        wpt[0 * D_DIM + t] = w4.x;
        wpt[1 * D_DIM + t] = w4.y;
        wpt[2 * D_DIM + t] = w4.z;
        wpt[3 * D_DIM + t] = w4.w;
    }
    const int cand = cand_ids[b];
    if (t >= 128 && t < 160) {
        int c = t - 128;
        ((float4*)candv)[c] = ((const float4*)(table + (long long)cand * D_DIM))[c];
    }
    rowids[t] = hist[(long long)b * H_LEN + t];

    float a0 = 0.f, a1 = 0.f, a2 = 0.f, a3 = 0.f;
    float l0 = 0.f, l1 = 0.f, l2 = 0.f, l3 = 0.f;

    for (int c = 0; c < NCH; ++c) {
        __syncthreads();

        const int   row = rowids[(c << 6) + r];
        const float* rp = table + (long long)row * D_DIM + (q << 2);
        float4 v0 = *(const float4*)(rp + 0 * 16);
        float4 v1 = *(const float4*)(rp + 1 * 16);
        float4 v2 = *(const float4*)(rp + 2 * 16);
        float4 v3 = *(const float4*)(rp + 3 * 16);
        float4 v4 = *(const float4*)(rp + 4 * 16);
        float4 v5 = *(const float4*)(rp + 5 * 16);
        float4 v6 = *(const float4*)(rp + 6 * 16);
        float4 v7 = *(const float4*)(rp + 7 * 16);

        float s0 = 0.f, s1 = 0.f, s2 = 0.f, s3 = 0.f;
        float4 va;
        #define DO_J(J, VV)                                                     \
        {   va = VV;                                                            \
            const int cb = (q << 2) + (J << 4);                                 \
            float4 w0 = *(const float4*)(wpt + 0 * D_DIM + cb);                 \
            float4 w1 = *(const float4*)(wpt + 1 * D_DIM + cb);                 \
            float4 w2 = *(const float4*)(wpt + 2 * D_DIM + cb);                 \
            float4 w3 = *(const float4*)(wpt + 3 * D_DIM + cb);                 \
            s0 += va.x * w0.x + va.y * w0.y + va.z * w0.z + va.w * w0.w;        \
            s1 += va.x * w1.x + va.y * w1.y + va.z * w1.z + va.w * w1.w;        \
            s2 += va.x * w2.x + va.y * w2.y + va.z * w2.z + va.w * w2.w;        \
            s3 += va.x * w3.x + va.y * w3.y + va.z * w3.z + va.w * w3.w;        \
            *(float4*)(tile + r * TPAD + cb) = va;                              \
        }
        DO_J(0, v0) DO_J(1, v1) DO_J(2, v2) DO_J(3, v3)
        DO_J(4, v4) DO_J(5, v5) DO_J(6, v6) DO_J(7, v7)
        #undef DO_J

        s0 += __shfl_xor(s0, 1); s0 += __shfl_xor(s0, 2);
        s1 += __shfl_xor(s1, 1); s1 += __shfl_xor(s1, 2);
        s2 += __shfl_xor(s2, 1); s2 += __shfl_xor(s2, 2);
        s3 += __shfl_xor(s3, 1); s3 += __shfl_xor(s3, 2);

        float e0 = expf(s0), e1 = expf(s1), e2 = expf(s2), e3 = expf(s3);
        if (q == 0) ((float4*)exps4)[r] = make_float4(e0, e1, e2, e3);

        float t0 = e0, t1 = e1, t2 = e2, t3 = e3;
        #pragma unroll
        for (int off = 4; off <= 32; off <<= 1) {
            t0 += __shfl_xor(t0, off);
            t1 += __shfl_xor(t1, off);
            t2 += __shfl_xor(t2, off);
            t3 += __shfl_xor(t3, off);
        }
        l0 += t0; l1 += t1; l2 += t2; l3 += t3;

        __syncthreads();

        #pragma unroll 8
        for (int i = 0; i < 32; ++i) {
            int hl = (half << 5) + i;
            float4 e4 = ((const float4*)exps4)[hl];
            float  vv = tile[hl * TPAD + d];
            a0 += e4.x * vv; a1 += e4.y * vv; a2 += e4.z * vv; a3 += e4.w * vv;
        }
    }

    __syncthreads();
    float* partBp = tile;
    float* ivbufp = tile + 512;

    if (half == 1) ((float4*)partBp)[d] = make_float4(a0, a1, a2, a3);
    if (lane == 0) ((float4*)lsumW)[w]  = make_float4(l0, l1, l2, l3);
    __syncthreads();

    float s0 = 0.f, s1 = 0.f, s2 = 0.f, s3 = 0.f;
    if (half == 0) {
        float4 pb = ((const float4*)partBp)[d];
        float4 L0 = ((const float4*)lsumW)[0];
        float4 L1 = ((const float4*)lsumW)[1];
        float4 L2 = ((const float4*)lsumW)[2];
        float4 L3 = ((const float4*)lsumW)[3];
        float i0 = 1.f / (L0.x + L1.x + L2.x + L3.x);
        float i1 = 1.f / (L0.y + L1.y + L2.y + L3.y);
        float i2 = 1.f / (L0.z + L1.z + L2.z + L3.z);
        float i3 = 1.f / (L0.w + L1.w + L2.w + L3.w);
        a0 = (a0 + pb.x) * i0;
        a1 = (a1 + pb.y) * i1;
        a2 = (a2 + pb.z) * i2;
        a3 = (a3 + pb.w) * i3;
        ((float4*)ivbufp)[d] = make_float4(a0, a1, a2, a3);
        float cd = candv[d];
        s0 = a0 * cd; s1 = a1 * cd; s2 = a2 * cd; s3 = a3 * cd;
    }
    #pragma unroll
    for (int off = 32; off >= 1; off >>= 1) {
        s0 += __shfl_xor(s0, off);
        s1 += __shfl_xor(s1, off);
        s2 += __shfl_xor(s2, off);
        s3 += __shfl_xor(s3, off);
    }
    if (lane == 0) {
        simred[w][0] = s0; simred[w][1] = s1;
        simred[w][2] = s2; simred[w][3] = s3;
    }
    __syncthreads();

    if (t == 0) {
        float sim[4];
        #pragma unroll
        for (int k = 0; k < 4; ++k)
            sim[k] = simred[0][k] + simred[1][k] + simred[2][k] + simred[3][k];
        int best = 0;
        #pragma unroll
        for (int k = 1; k < 4; ++k) if (sim[k] > sim[best]) best = k;
        bestk = best;
    }
    __syncthreads();

    __hip_bfloat16* xrow = Xbf + (long long)b * (2 * D_DIM);
    if (t < 128) xrow[t] = __float2bfloat16(ivbufp[t * 4 + bestk]);
    else         xrow[t] = __float2bfloat16(candv[t - 128]);
}

// ---------------------------------------------------------------------------
// Fused MLP tail (unchanged from round 8): layer1 -> LDS -> layer2 -> head.
// ---------------------------------------------------------------------------
__global__ __launch_bounds__(256) void fused_mlp(
    const __hip_bfloat16* __restrict__ Xbf,
    const __hip_bfloat16* __restrict__ W1t,
    const float* __restrict__ b1,
    const __hip_bfloat16* __restrict__ W2t,
    const float* __restrict__ b2,
    const float* __restrict__ W3,
    const float* __restrict__ b3,
    float* __restrict__ out)
{
    __shared__ __hip_bfloat16 H1s[64 * H1PAD];

    const int t    = threadIdx.x;
    const int wave = t >> 6, lane = t & 63;
    const int lm   = lane & 15, quad = lane >> 4;
    const int mrow = blockIdx.x * 64 + wave * 16;
    const int lrow = wave * 16;

    const __hip_bfloat16* Ap = Xbf + (long long)(mrow + lm) * 256 + quad * 8;
    bf16x8 afr[8];
    #pragma unroll
    for (int j = 0; j < 8; ++j) afr[j] = *(const bf16x8*)(Ap + j * 32);

    #pragma unroll 4
    for (int nt = 0; nt < 32; ++nt) {
        const int n = nt * 16 + lm;
        const __hip_bfloat16* Bp = W1t + (long long)n * 256 + quad * 8;
        f32x4 acc = {0.f, 0.f, 0.f, 0.f};
        #pragma unroll
        for (int j = 0; j < 8; ++j) {
            bf16x8 bfr = *(const bf16x8*)(Bp + j * 32);
            acc = __builtin_amdgcn_mfma_f32_16x16x32_bf16(afr[j], bfr, acc, 0, 0, 0);
        }
        const float bv = b1[n];
        #pragma unroll
        for (int i = 0; i < 4; ++i) {
            float v = fmaxf(acc[i] + bv, 0.f);
            H1s[(lrow + quad * 4 + i) * H1PAD + n] = __float2bfloat16(v);
        }
    }

    bf16x8 hfr[16];
    #pragma unroll
    for (int j = 0; j < 16; ++j)
        hfr[j] = *(const bf16x8*)(&H1s[(lrow + lm) * H1PAD + j * 32 + quad * 8]);

    float hp[4] = {0.f, 0.f, 0.f, 0.f};
    #pragma unroll 2
    for (int nt = 0; nt < 16; ++nt) {
        const int n = nt * 16 + lm;
        const __hip_bfloat16* Bp = W2t + (long long)n * 512 + quad * 8;
        f32x4 acc = {0.f, 0.f, 0.f, 0.f};
        #pragma unroll
        for (int j = 0; j < 16; ++j) {
            bf16x8 bfr = *(const bf16x8*)(Bp + j * 32);
            acc = __builtin_amdgcn_mfma_f32_16x16x32_bf16(hfr[j], bfr, acc, 0, 0, 0);
        }
        const float bv = b2[n], w3v = W3[n];
        #pragma unroll
        for (int i = 0; i < 4; ++i)
            hp[i] += fmaxf(acc[i] + bv, 0.f) * w3v;
    }

    #pragma unroll
    for (int off = 1; off <= 8; off <<= 1) {
        hp[0] += __shfl_xor(hp[0], off);
        hp[1] += __shfl_xor(hp[1], off);
        hp[2] += __shfl_xor(hp[2], off);
        hp[3] += __shfl_xor(hp[3], off);
    }
    if (lm == 0) {
        const float bb = b3[0];
        #pragma unroll
        for (int i = 0; i < 4; ++i) {
            float z = hp[i] + bb;
            out[mrow + quad * 4 + i] = 1.f / (1.f + expf(-z));
        }
    }
}

// ---------------------------------------------------------------------------
extern "C" void kernel_launch(void* const* d_in, const int* in_sizes, int n_in,
                              void* d_out, int out_size, void* d_ws, size_t ws_size,
                              hipStream_t stream) {
    const int*   cand  = (const int*)  d_in[1];
    const int*   hist  = (const int*)  d_in[2];
    const float* table = (const float*)d_in[3];
    const float* Wp    = (const float*)d_in[4];
    const float* W1    = (const float*)d_in[5];
    const float* b1    = (const float*)d_in[6];
    const float* W2    = (const float*)d_in[7];
    const float* b2    = (const float*)d_in[8];
    const float* W3    = (const float*)d_in[9];
    const float* b3    = (const float*)d_in[10];
    float* out = (float*)d_out;

    const size_t t16_bytes = (size_t)NUM_ITEMS * D_DIM * 2;      // 51.2 MB
    const size_t xbf_bytes = (size_t)B_SZ * 2 * D_DIM * 2;       // 2 MB
    const size_t w1t_bytes = (size_t)H1_DIM * 2 * D_DIM * 2;     // 512 KB
    const size_t w2t_bytes = (size_t)H2_DIM * H1_DIM * 2;        // 256 KB
    const bool   use16 = ws_size >= t16_bytes + xbf_bytes + w1t_bytes + w2t_bytes;

    char* p = (char*)d_ws;
    _Float16* t16 = nullptr;
    if (use16) { t16 = (_Float16*)p; p += t16_bytes; }
    __hip_bfloat16* Xbf = (__hip_bfloat16*)p;  p += xbf_bytes;
    __hip_bfloat16* W1t = (__hip_bfloat16*)p;  p += w1t_bytes;
    __hip_bfloat16* W2t = (__hip_bfloat16*)p;

    if (use16) {
        convert_table<<<(NUM_ITEMS * D_DIM / 8) / 256, 256, 0, stream>>>(table, t16);
        interest_kernel_f16<<<B_SZ + 1024, 256, 0, stream>>>(
            cand, hist, table, t16, Wp, W1, W2, W1t, W2t, Xbf);
    } else {
        interest_kernel_f32<<<B_SZ + 1024, 256, 0, stream>>>(
            cand, hist, table, Wp, W1, W2, W1t, W2t, Xbf);
    }
    fused_mlp<<<B_SZ / 64, 256, 0, stream>>>(Xbf, W1t, b1, W2t, b2, W3, b3, out);
}